// Round 10
// baseline (128.936 us; speedup 1.0000x reference)
//
#include <hip/hip_runtime.h>
#include <stdint.h>

#define BATCH 16
#define CH    256
#define CI    128
#define NSP   4096
#define KC    4          // K-split chunks for the Gram GEMM
#define EPSV  1e-5f

typedef unsigned short u16;
typedef __attribute__((ext_vector_type(4))) float f32x4;
typedef __attribute__((ext_vector_type(8))) short bf16x8;

__device__ __forceinline__ u16 f2b(float f) {
  uint32_t u = __float_as_uint(f);
  uint32_t r = u + 0x7FFFu + ((u >> 16) & 1u);   // round-to-nearest-even
  return (u16)(r >> 16);
}

__device__ __forceinline__ void async16(void* lds, const void* g) {
  __builtin_amdgcn_global_load_lds(
      (const __attribute__((address_space(1))) unsigned int*)g,
      (__attribute__((address_space(3))) unsigned int*)lds, 16, 0, 0);
}

// ---------------- k_prep2: pure stream — x f32 -> Xb bf16 (16B stores) + psum.
// grid (64, 4, 17): z<16 = batch slices; z==16 = merged const roles (R9-proven).
__global__ __launch_bounds__(256) void k_prep2(const float* __restrict__ x,
    u16* __restrict__ xb, float* __restrict__ psum,
    const float* __restrict__ w_w, const float* __restrict__ g_w,
    const float* __restrict__ g_b, const float* __restrict__ theta_w,
    const float* __restrict__ theta_b, const float* __restrict__ phi_w,
    const float* __restrict__ phi_b, const float* __restrict__ w_b,
    const float* __restrict__ bn_g, const float* __restrict__ bn_b,
    const float* __restrict__ bn_m, const float* __restrict__ bn_v,
    float* __restrict__ E, float* __restrict__ KT, float* __restrict__ wg,
    float* __restrict__ tphi, float* __restrict__ q, float* __restrict__ inv,
    float* __restrict__ dconst, float* __restrict__ tb) {
  __shared__ float lbuf[1024];
  const int t = threadIdx.x;
  if (blockIdx.z == BATCH) {                 // ---- const role (R9 body, unchanged)
    const int id = blockIdx.y*64 + blockIdx.x;
    if (id < 32) {
      const int o0 = id*8;
      #pragma unroll
      for (int k = 0; k < 4; ++k) { int idx = k*256 + t;
        lbuf[idx] = w_w[(size_t)(o0 + (idx & 7))*CI + (idx >> 3)]; }
      __syncthreads();
      float acc[8] = {0.f};
      for (int j = 0; j < CI; ++j) {
        float gv = g_w[(size_t)j*CH + t];
        #pragma unroll
        for (int r = 0; r < 8; ++r) acc[r] += lbuf[j*8 + r] * gv;
      }
      #pragma unroll
      for (int r = 0; r < 8; ++r) E[(size_t)(o0 + r)*CH + t] = acc[r];
    } else if (id < 64) {
      const int a0 = (id - 32)*8;
      #pragma unroll
      for (int k = 0; k < 4; ++k) { int idx = k*256 + t;
        lbuf[idx] = phi_w[(size_t)(idx >> 3)*CH + a0 + (idx & 7)]; }
      __syncthreads();
      float acc[8] = {0.f};
      for (int i = 0; i < CI; ++i) {
        float tv = theta_w[(size_t)i*CH + t];
        #pragma unroll
        for (int u = 0; u < 8; ++u) acc[u] += lbuf[i*8 + u] * tv;
      }
      #pragma unroll
      for (int u = 0; u < 8; ++u) KT[(size_t)(a0 + u)*CH + t] = acc[u];
    } else if (id == 64) {
      float iv = bn_g[t] * rsqrtf(bn_v[t] + EPSV);
      inv[t] = iv;
      dconst[t] = iv*w_b[t] + bn_b[t] - bn_m[t]*iv;
      float a = 0.f;
      for (int j = 0; j < CI; ++j) a += w_w[(size_t)t*CI + j] * g_b[j];
      wg[t] = a;
      float tp = 0.f, qq = 0.f;
      for (int i = 0; i < CI; ++i) {
        tp += theta_w[(size_t)i*CH + t] * phi_b[i];
        qq += phi_w[(size_t)i*CH + t] * theta_b[i];
      }
      tphi[t] = tp; q[t] = qq;
      lbuf[t] = (t < CI) ? theta_b[t]*phi_b[t] : 0.f;
      __syncthreads();
      for (int s2 = 128; s2 > 0; s2 >>= 1) { if (t < s2) lbuf[t] += lbuf[t + s2]; __syncthreads(); }
      if (t == 0) tb[0] = lbuf[0];
    }
    return;
  }
  // ---- streaming role: 64c x 64n tile, no LDS, no barriers
  const int b = blockIdx.z, c0 = blockIdx.y*64, n0 = blockIdx.x*64;
  const int lane8 = t & 7, rq = t >> 3;        // rq 0..31
  const float* xp = x + ((size_t)b*CH + c0)*NSP + n0 + lane8*8;
  u16* xbp = xb + ((size_t)b*CH + c0)*NSP + n0 + lane8*8;
  #pragma unroll
  for (int p = 0; p < 2; ++p) {
    const int cl = rq + p*32;
    float4 v0 = *(const float4*)(xp + (size_t)cl*NSP);
    float4 v1 = *(const float4*)(xp + (size_t)cl*NSP + 4);
    float ps = v0.x+v0.y+v0.z+v0.w + v1.x+v1.y+v1.z+v1.w;
    #pragma unroll
    for (int o = 1; o < 8; o <<= 1) ps += __shfl_xor(ps, o, 64);
    if (lane8 == 0) psum[((size_t)b*64 + blockIdx.x)*CH + c0 + cl] = ps;
    bf16x8 bv;
    bv[0]=(short)f2b(v0.x); bv[1]=(short)f2b(v0.y); bv[2]=(short)f2b(v0.z); bv[3]=(short)f2b(v0.w);
    bv[4]=(short)f2b(v1.x); bv[5]=(short)f2b(v1.y); bv[6]=(short)f2b(v1.z); bv[7]=(short)f2b(v1.w);
    *(bf16x8*)(xbp + (size_t)cl*NSP) = bv;
  }
}

// ---------------- k_tr: Xb [b][c][n] bf16 -> XT [b][n][c] bf16.
// Tile 64n x 256c, LDS [64n][256c] u16 with col swizzle c ^ (((n>>3)&7)<<3).
// Store: scalar u16, bank = (rowq>>1) + 4*lane8 -> 2 lanes/bank (free).
// Read: bf16x8 with same key (multiple of 8 => inversion exact).
// XT write: 512B fully contiguous per n row.
__global__ __launch_bounds__(256) void k_tr(const u16* __restrict__ xb, u16* __restrict__ xt) {
  __shared__ u16 tl[64*256];   // 32 KB
  const int b = blockIdx.y, n0 = blockIdx.x*64;
  const int t = threadIdx.x;
  const int lane8 = t & 7, rq = t >> 3;        // rq 0..31
  const u16* src = xb + (size_t)b*CH*NSP + n0;
  #pragma unroll
  for (int p = 0; p < 8; ++p) {
    const int c = rq + p*32;                   // 0..255
    bf16x8 v = *(const bf16x8*)(src + (size_t)c*NSP + lane8*8);
    const int cs = c ^ (lane8 << 3);           // key: n>>3 = lane8 for all 8 elems
    #pragma unroll
    for (int j = 0; j < 8; ++j)
      tl[(lane8*8 + j)*256 + cs] = (u16)v[j];
  }
  __syncthreads();
  const int c8 = t & 31, nl = t >> 5;          // c8: 8-col group, nl 0..7
  u16* dst = xt + ((size_t)b*NSP + n0)*CH;
  #pragma unroll
  for (int p2 = 0; p2 < 8; ++p2) {
    const int n = p2*8 + nl;                   // n>>3 = p2 (uniform per instr)
    bf16x8 v = *(const bf16x8*)(tl + n*256 + ((c8*8) ^ (p2 << 3)));
    *(bf16x8*)(dst + (size_t)n*CH + c8*8) = v;
  }
}

// ---------------- kernel 2: Gram partials, 64x64 symmetric tiles (10 of 16), KC=4
__global__ __launch_bounds__(256) void k_gram(const u16* __restrict__ xb, float* __restrict__ Sp) {
  __shared__ u16 As[64*64];   // 8 KB
  __shared__ u16 Bs[64*64];   // 8 KB
  const int TIa[10] = {0,0,0,0,1,1,1,2,2,3};
  const int TJa[10] = {0,1,2,3,1,2,3,2,3,3};
  const int L = blockIdx.x;
  const int wk = (L & 7) * 80 + (L >> 3);   // bijective: 640 = 8*80
  const int b = wk / 40;
  const int rem = wk % 40;
  const int kc = rem / 10;
  const int tile = rem % 10;
  const int ti = TIa[tile], tj = TJa[tile];
  const int m_base = ti*64, n_base = tj*64;
  const bool diag = (ti == tj);
  const int t = threadIdx.x, wv = t >> 6, l = t & 63;
  const int wr = wv >> 1, wc = wv & 1;
  const int lr = l & 15, lkb = l >> 4;      // fragment row lane, k sub-block
  const int sr8 = l >> 3, ss = l & 7;       // staging: row-within-8, 16B slot
  const u16* xa = xb + (size_t)b*CH*NSP;
  const int kbeg = kc * (NSP/KC);
  f32x4 acc[2][2];
  #pragma unroll
  for (int i = 0; i < 2; ++i)
    #pragma unroll
    for (int j = 0; j < 2; ++j) acc[i][j] = (f32x4){0.f,0.f,0.f,0.f};

  for (int kk = 0; kk < 16; ++kk) {
    const int kpos = kbeg + kk*64;
    #pragma unroll
    for (int j = 0; j < 2; ++j) {
      const int g = wv*2 + j;               // 0..7
      const int r = g*8 + sr8;              // 0..63
      async16(&As[g*512], xa + (size_t)(m_base + r)*NSP + kpos + ((ss ^ (r & 7)) * 8));
    }
    if (!diag) {
      #pragma unroll
      for (int j = 0; j < 2; ++j) {
        const int g = wv*2 + j;
        const int r = g*8 + sr8;
        async16(&Bs[g*512], xa + (size_t)(n_base + r)*NSP + kpos + ((ss ^ (r & 7)) * 8));
      }
    }
    __syncthreads();
    const u16* bsrc = diag ? As : Bs;
    #pragma unroll
    for (int ks = 0; ks < 2; ++ks) {
      bf16x8 A[2], Bf[2];
      #pragma unroll
      for (int mt = 0; mt < 2; ++mt) {
        const int ra = wr*32 + mt*16 + lr;
        A[mt] = *(const bf16x8*)(As + ra*64 + (((ks*4 + lkb) ^ (ra & 7)) * 8));
      }
      #pragma unroll
      for (int nt = 0; nt < 2; ++nt) {
        const int rb = wc*32 + nt*16 + lr;
        Bf[nt] = *(const bf16x8*)(bsrc + rb*64 + (((ks*4 + lkb) ^ (rb & 7)) * 8));
      }
      #pragma unroll
      for (int mt = 0; mt < 2; ++mt)
        #pragma unroll
        for (int nt = 0; nt < 2; ++nt)
          acc[mt][nt] = __builtin_amdgcn_mfma_f32_16x16x32_bf16(A[mt], Bf[nt], acc[mt][nt], 0, 0, 0);
    }
    __syncthreads();
  }
  float* Sb = Sp + (size_t)((b*KC + kc)*10 + tile)*4096;
  const int r0 = (l >> 4) * 4;
  #pragma unroll
  for (int mt = 0; mt < 2; ++mt)
    #pragma unroll
    for (int nt = 0; nt < 2; ++nt)
      #pragma unroll
      for (int rr = 0; rr < 4; ++rr) {
        const int lm = wr*32 + mt*16 + r0 + rr;
        const int lc = wc*32 + nt*16 + lr;
        Sb[lm*64 + lc] = acc[mt][nt][rr];
      }
}

// ---------------- fused: reduce Sp tiles -> S (with symmetric mirror) + per-batch vectors
__global__ __launch_bounds__(256) void k_redvec(const float* __restrict__ Sp,
    const float* __restrict__ psum, const float* __restrict__ E,
    const float* __restrict__ KT, const float* __restrict__ q,
    float* __restrict__ S, float* __restrict__ KS, float* __restrict__ Es,
    float* __restrict__ qs) {
  __shared__ float tl[64*65 + 8];
  const int b = blockIdx.y, xx = blockIdx.x, t = threadIdx.x;
  if (xx < 10) {
    const int TIa[10] = {0,0,0,0,1,1,1,2,2,3};
    const int TJa[10] = {0,1,2,3,1,2,3,2,3,3};
    const int ti = TIa[xx], tj = TJa[xx];
    const int row0 = ti*64, col0 = tj*64;
    float* Sb = S + (size_t)b*CH*CH;
    float4 sum[4];
    #pragma unroll
    for (int k = 0; k < 4; ++k) {
      const int slot = t + k*256;
      const int r = slot >> 4, c4 = (slot & 15) * 4;
      float4 s = {0.f,0.f,0.f,0.f};
      #pragma unroll
      for (int kc = 0; kc < KC; ++kc) {
        const float* p = Sp + (size_t)((b*KC + kc)*10 + xx)*4096;
        float4 v = *(const float4*)(p + r*64 + c4);
        s.x += v.x; s.y += v.y; s.z += v.z; s.w += v.w;
      }
      sum[k] = s;
      *(float4*)(Sb + (size_t)(row0 + r)*CH + col0 + c4) = s;
    }
    if (ti != tj) {                            // mirror to lower triangle
      #pragma unroll
      for (int k = 0; k < 4; ++k) {
        const int slot = t + k*256;
        const int r = slot >> 4, c4 = (slot & 15) * 4;
        tl[r*65 + c4+0] = sum[k].x; tl[r*65 + c4+1] = sum[k].y;
        tl[r*65 + c4+2] = sum[k].z; tl[r*65 + c4+3] = sum[k].w;
      }
      __syncthreads();
      #pragma unroll
      for (int k = 0; k < 4; ++k) {
        const int slot = t + k*256;
        const int r = slot >> 4, c4 = (slot & 15) * 4;
        float4 v = { tl[(c4+0)*65 + r], tl[(c4+1)*65 + r],
                     tl[(c4+2)*65 + r], tl[(c4+3)*65 + r] };
        *(float4*)(Sb + (size_t)(col0 + r)*CH + row0 + c4) = v;
      }
    }
  } else {
    float s = 0.f;
    for (int nb = 0; nb < 64; ++nb) s += psum[((size_t)b*64 + nb)*CH + t];
    tl[t] = s;
    __syncthreads();
    float ks = 0.f;
    for (int a = 0; a < CH; ++a) ks += KT[(size_t)a*CH + t] * tl[a];
    KS[(size_t)b*CH + t] = ks;
    float es = 0.f;
    for (int c = 0; c < CH; ++c) es += E[(size_t)t*CH + c] * tl[c];
    Es[(size_t)b*CH + t] = es;
    float p = q[t] * tl[t];
    #pragma unroll
    for (int o = 1; o < 64; o <<= 1) p += __shfl_xor(p, o, 64);
    if ((t & 63) == 0) tl[4160 + (t >> 6)] = p;
    __syncthreads();
    if (t == 0) qs[b] = tl[4160] + tl[4161] + tl[4162] + tl[4163];
  }
}

// ---------------- k_RP: fused R = E·S (LDS-resident) then P = (inv/N)(R·KT + rank1s) + I
__global__ __launch_bounds__(256) void k_RP(const float* __restrict__ S,
    const float* __restrict__ E, const float* __restrict__ KT,
    const float* __restrict__ q, const float* __restrict__ KS,
    const float* __restrict__ Es, const float* __restrict__ qs,
    const float* __restrict__ wg, const float* __restrict__ tphi,
    const float* __restrict__ inv, const float* __restrict__ dconst,
    const float* __restrict__ tb, u16* __restrict__ Pb, float* __restrict__ dv) {
  __shared__ float lEt[2048];
  __shared__ float lRt[2048];
  __shared__ float red[32];
  const int b = blockIdx.y, o0 = blockIdx.x*8, t = threadIdx.x;
  #pragma unroll
  for (int k = 0; k < 8; ++k) { int idx = k*256 + t;
    lEt[idx] = E[(size_t)(o0 + (idx & 7))*CH + (idx >> 3)]; }
  __syncthreads();
  const float* Sb = S + (size_t)b*CH*CH;
  float acc[8] = {0.f};
  for (int c = 0; c < CH; ++c) {
    float sv = Sb[(size_t)c*CH + t];
    #pragma unroll
    for (int r = 0; r < 8; ++r) acc[r] += lEt[c*8 + r] * sv;
  }
  #pragma unroll
  for (int r = 0; r < 8; ++r) lRt[t*8 + r] = acc[r];
  const float qt = q[t];
  #pragma unroll
  for (int r = 0; r < 8; ++r) {
    float p = acc[r] * qt;
    #pragma unroll
    for (int o = 1; o < 64; o <<= 1) p += __shfl_xor(p, o, 64);
    if ((t & 63) == 0) red[r*4 + (t >> 6)] = p;
  }
  __syncthreads();
  float acc2[8] = {0.f};
  for (int a = 0; a < CH; ++a) {
    float kv = KT[(size_t)a*CH + t];
    #pragma unroll
    for (int r = 0; r < 8; ++r) acc2[r] += lRt[a*8 + r] * kv;
  }
  const float ksv = KS[(size_t)b*CH + t], tpv = tphi[t];
  u16* Pbb = Pb + (size_t)b*CH*CH;
  #pragma unroll
  for (int r = 0; r < 8; ++r) {
    int o = o0 + r;
    float val = (acc2[r] + wg[o]*ksv + (Es[(size_t)b*CH + o] + (float)NSP*wg[o])*tpv)
                * inv[o] * (1.f/(float)NSP);
    if (o == t) val += 1.f;      // fold residual: P + I
    Pbb[(size_t)o*CH + t] = f2b(val);
  }
  if (t < 8) {
    int o = o0 + t;
    float iv = inv[o], wgo = wg[o], tb0 = tb[0];
    float rq = red[t*4] + red[t*4+1] + red[t*4+2] + red[t*4+3];
    float t2 = rq + wgo*qs[b] + Es[(size_t)b*CH + o]*tb0;
    dv[(size_t)b*CH + o] = iv*(t2*(1.f/(float)NSP) + wgo*tb0) + dconst[o];
  }
}

// ---------------- apply: out = (P+I) X + d 1^T  (LDS-staged B, coalesced f32 epilogue)
__global__ __launch_bounds__(512, 4) void k_apply(const u16* __restrict__ Pb,
    const u16* __restrict__ xt, const float* __restrict__ dv,
    float* __restrict__ out) {
  __shared__ union {
    u16   bx[64*256];        // 32 KB bf16 B-tile (XOR-swizzled 16B slots)
    float fe[8][16][68];     // 34 KB per-wave f32 epilogue buffers (stride 68)
  } sm;
  const int b = blockIdx.y, n0 = blockIdx.x*64;
  const int t = threadIdx.x, w = t >> 6, l = t & 63;
  {
    const u16* src = xt + ((size_t)b*NSP + n0)*CH;
    const int r = t >> 3, sbase = t & 7;
    #pragma unroll
    for (int it = 0; it < 4; ++it) {
      int slot = sbase + it*8;         // 0..31 (16B slots within 512B row)
      bf16x8 v = *(const bf16x8*)(src + (size_t)r*CH + slot*8);
      *(bf16x8*)(sm.bx + r*256 + ((slot ^ (r & 7)) * 8)) = v;
    }
  }
  __syncthreads();
  const int m0 = w*32;
  const int lr = l & 15, lkb = l >> 4;   // k sub-block 0..3 (8 elems each)
  const int sw = lr & 7;
  const u16* Pp = Pb + (size_t)b*CH*CH;
  f32x4 acc[2][4];
  #pragma unroll
  for (int i = 0; i < 2; ++i)
    #pragma unroll
    for (int j = 0; j < 4; ++j) acc[i][j] = (f32x4){0.f,0.f,0.f,0.f};
  #pragma unroll
  for (int kk = 0; kk < 8; ++kk) {
    bf16x8 A[2], Bf[4];
    #pragma unroll
    for (int mt = 0; mt < 2; ++mt)
      A[mt] = *(const bf16x8*)(Pp + (size_t)(m0 + mt*16 + lr)*CH + kk*32 + lkb*8);
    #pragma unroll
    for (int nt = 0; nt < 4; ++nt) {
      int slot = kk*4 + lkb;
      Bf[nt] = *(const bf16x8*)(sm.bx + (nt*16 + lr)*256 + ((slot ^ sw) * 8));
    }
    #pragma unroll
    for (int mt = 0; mt < 2; ++mt)
      #pragma unroll
      for (int nt = 0; nt < 4; ++nt)
        acc[mt][nt] = __builtin_amdgcn_mfma_f32_16x16x32_bf16(A[mt], Bf[nt], acc[mt][nt], 0, 0, 0);
  }
  __syncthreads();                     // B-tile dead; reuse LDS for epilogue
  float* ob = out + (size_t)b*CH*NSP;
  const int r0 = (l >> 4) * 4;
  #pragma unroll
  for (int mt = 0; mt < 2; ++mt) {
    #pragma unroll
    for (int rr = 0; rr < 4; ++rr) {
      float dval = dv[(size_t)b*CH + m0 + mt*16 + r0 + rr];
      #pragma unroll
      for (int nt = 0; nt < 4; ++nt)
        sm.fe[w][r0 + rr][nt*16 + lr] = acc[mt][nt][rr] + dval;
    }
    #pragma unroll
    for (int i = 0; i < 4; ++i) {
      int s = l + 64*i;
      int rrow = s >> 4, c4 = (s & 15) * 4;
      float4 v = *(const float4*)&sm.fe[w][rrow][c4];
      *(float4*)&ob[(size_t)(m0 + mt*16 + rrow)*NSP + n0 + c4] = v;
    }
  }
}

// ---------------- workspace layout (bytes)
static constexpr size_t XT_OFF = 0;              // bf16 [16][4096][256]  33,554,432
static constexpr size_t S_OFF  = 33554432;       // f32  [16][256][256]    4,194,304
static constexpr size_t PB_OFF = 37748736;       // bf16 [16][256][256]    2,097,152
static constexpr size_t PS_OFF = 39845888;       // f32  [16][64][256]     1,048,576
static constexpr size_t E_OFF  = 40894464;       // f32  [256][256]          262,144
static constexpr size_t KT_OFF = 41156608;       // f32  [256][256]          262,144
static constexpr size_t WG_OFF = 41418752;       // f32 [256] (1K pad each follows)
static constexpr size_t TP_OFF = 41419776;
static constexpr size_t QV_OFF = 41420800;
static constexpr size_t IV_OFF = 41421824;
static constexpr size_t DC_OFF = 41422848;
static constexpr size_t TB_OFF = 41423872;
static constexpr size_t KS_OFF = 41424896;       // f32 [16][256] 16,384
static constexpr size_t ES_OFF = 41441280;       // f32 [16][256] 16,384
static constexpr size_t QS_OFF = 41457664;       // f32 [16] (1K pad)
static constexpr size_t DV_OFF = 41458688;       // f32 [16][256] 16,384

extern "C" void kernel_launch(void* const* d_in, const int* in_sizes, int n_in,
                              void* d_out, int out_size, void* d_ws, size_t ws_size,
                              hipStream_t stream) {
  const float* x       = (const float*)d_in[0];
  const float* g_w     = (const float*)d_in[1];
  const float* g_b     = (const float*)d_in[2];
  const float* theta_w = (const float*)d_in[3];
  const float* theta_b = (const float*)d_in[4];
  const float* phi_w   = (const float*)d_in[5];
  const float* phi_b   = (const float*)d_in[6];
  const float* w_w     = (const float*)d_in[7];
  const float* w_b     = (const float*)d_in[8];
  const float* bn_g    = (const float*)d_in[9];
  const float* bn_b    = (const float*)d_in[10];
  const float* bn_m    = (const float*)d_in[11];
  const float* bn_v    = (const float*)d_in[12];
  float* out = (float*)d_out;
  char* ws = (char*)d_ws;
  u16*   XT = (u16*)(ws + XT_OFF);
  float* S  = (float*)(ws + S_OFF);
  u16*   Pb = (u16*)(ws + PB_OFF);
  float* PS = (float*)(ws + PS_OFF);
  float* E  = (float*)(ws + E_OFF);
  float* KT = (float*)(ws + KT_OFF);
  float* WG = (float*)(ws + WG_OFF);
  float* TP = (float*)(ws + TP_OFF);
  float* QV = (float*)(ws + QV_OFF);
  float* IV = (float*)(ws + IV_OFF);
  float* DC = (float*)(ws + DC_OFF);
  float* TB = (float*)(ws + TB_OFF);
  float* KS = (float*)(ws + KS_OFF);
  float* ES = (float*)(ws + ES_OFF);
  float* QS = (float*)(ws + QS_OFF);
  float* DV = (float*)(ws + DV_OFF);
  // d_out scratch: Xb bf16 [0, 33.5MB); compact Sp [33.5MB, +10.5MB). Dead before k_apply.
  u16*   Xb = (u16*)d_out;
  float* Sp = (float*)((char*)d_out + 33554432);

  k_prep2 <<<dim3(64, 4, BATCH+1),        256, 0, stream>>>(x, Xb, PS,
            w_w, g_w, g_b, theta_w, theta_b, phi_w, phi_b, w_b, bn_g, bn_b, bn_m, bn_v,
            E, KT, WG, TP, QV, IV, DC, TB);
  k_gram  <<<dim3(640),                   256, 0, stream>>>(Xb, Sp);
  k_tr    <<<dim3(64, BATCH),             256, 0, stream>>>(Xb, XT);
  k_redvec<<<dim3(11, BATCH),             256, 0, stream>>>(Sp, PS, E, KT, QV, S, KS, ES, QS);
  k_RP    <<<dim3(32, BATCH),             256, 0, stream>>>(S, E, KT, QV, KS, ES, QS, WG, TP, IV, DC, TB, Pb, DV);
  k_apply <<<dim3(NSP/64, BATCH),         512, 0, stream>>>(Pb, XT, DV, out);
}

// Round 11
// 120.202 us; speedup vs baseline: 1.0727x; 1.0727x over previous
//
#include <hip/hip_runtime.h>
#include <stdint.h>

#define BATCH 16
#define CH    256
#define CI    128
#define NSP   4096
#define KC    4          // K-split chunks for the Gram GEMM
#define EPSV  1e-5f

typedef unsigned short u16;
typedef __attribute__((ext_vector_type(4))) float f32x4;
typedef __attribute__((ext_vector_type(8))) short bf16x8;

__device__ __forceinline__ u16 f2b(float f) {
  uint32_t u = __float_as_uint(f);
  uint32_t r = u + 0x7FFFu + ((u >> 16) & 1u);   // round-to-nearest-even
  return (u16)(r >> 16);
}

__device__ __forceinline__ void async16(void* lds, const void* g) {
  __builtin_amdgcn_global_load_lds(
      (const __attribute__((address_space(1))) unsigned int*)g,
      (__attribute__((address_space(3))) unsigned int*)lds, 16, 0, 0);
}

// ---------------- k_prep: x f32 -> Xb bf16 + XT bf16 (transposed) + psum, x read ONCE.
// grid (65, 1, 17): z<16, x<64 = batch slices (tile 256c x 64n); z==16 = const roles.
// LDS: bf16 [64n][256c], col swizzle c ^ (((n>>3)&7)<<3)  (R10 k_tr-verified).
// Store phase: scalar u16, (cs>>1)%32 hits each bank exactly 2x = free.
// XT write phase: fully contiguous 512B per n row (R10 k_tr-verified).
__global__ __launch_bounds__(256) void k_prep(const float* __restrict__ x,
    u16* __restrict__ xb, u16* __restrict__ xt, float* __restrict__ psum,
    const float* __restrict__ w_w, const float* __restrict__ g_w,
    const float* __restrict__ g_b, const float* __restrict__ theta_w,
    const float* __restrict__ theta_b, const float* __restrict__ phi_w,
    const float* __restrict__ phi_b, const float* __restrict__ w_b,
    const float* __restrict__ bn_g, const float* __restrict__ bn_b,
    const float* __restrict__ bn_m, const float* __restrict__ bn_v,
    float* __restrict__ E, float* __restrict__ KT, float* __restrict__ wg,
    float* __restrict__ tphi, float* __restrict__ q, float* __restrict__ inv,
    float* __restrict__ dconst, float* __restrict__ tb) {
  __shared__ union { u16 tl[64*256]; float lbuf[1024]; } sm;   // 32 KB
  const int t = threadIdx.x;
  if (blockIdx.z == BATCH) {                 // ---- const role (R9 body; id = x)
    float* lbuf = sm.lbuf;
    const int id = blockIdx.x;
    if (id < 32) {
      const int o0 = id*8;
      #pragma unroll
      for (int k = 0; k < 4; ++k) { int idx = k*256 + t;
        lbuf[idx] = w_w[(size_t)(o0 + (idx & 7))*CI + (idx >> 3)]; }
      __syncthreads();
      float acc[8] = {0.f};
      for (int j = 0; j < CI; ++j) {
        float gv = g_w[(size_t)j*CH + t];
        #pragma unroll
        for (int r = 0; r < 8; ++r) acc[r] += lbuf[j*8 + r] * gv;
      }
      #pragma unroll
      for (int r = 0; r < 8; ++r) E[(size_t)(o0 + r)*CH + t] = acc[r];
    } else if (id < 64) {
      const int a0 = (id - 32)*8;
      #pragma unroll
      for (int k = 0; k < 4; ++k) { int idx = k*256 + t;
        lbuf[idx] = phi_w[(size_t)(idx >> 3)*CH + a0 + (idx & 7)]; }
      __syncthreads();
      float acc[8] = {0.f};
      for (int i = 0; i < CI; ++i) {
        float tv = theta_w[(size_t)i*CH + t];
        #pragma unroll
        for (int u = 0; u < 8; ++u) acc[u] += lbuf[i*8 + u] * tv;
      }
      #pragma unroll
      for (int u = 0; u < 8; ++u) KT[(size_t)(a0 + u)*CH + t] = acc[u];
    } else if (id == 64) {
      float iv = bn_g[t] * rsqrtf(bn_v[t] + EPSV);
      inv[t] = iv;
      dconst[t] = iv*w_b[t] + bn_b[t] - bn_m[t]*iv;
      float a = 0.f;
      for (int j = 0; j < CI; ++j) a += w_w[(size_t)t*CI + j] * g_b[j];
      wg[t] = a;
      float tp = 0.f, qq = 0.f;
      for (int i = 0; i < CI; ++i) {
        tp += theta_w[(size_t)i*CH + t] * phi_b[i];
        qq += phi_w[(size_t)i*CH + t] * theta_b[i];
      }
      tphi[t] = tp; q[t] = qq;
      lbuf[t] = (t < CI) ? theta_b[t]*phi_b[t] : 0.f;
      __syncthreads();
      for (int s2 = 128; s2 > 0; s2 >>= 1) { if (t < s2) lbuf[t] += lbuf[t + s2]; __syncthreads(); }
      if (t == 0) tb[0] = lbuf[0];
    }
    return;
  }
  if (blockIdx.x >= 64) return;              // streaming role uses x 0..63
  // ---- streaming role: read x once, write Xb + LDS-transposed bf16
  const int b = blockIdx.z, n0 = blockIdx.x*64;
  const int lane8 = t & 7, rq = t >> 3;      // rq 0..31
  const float* xp = x + (size_t)b*CH*NSP + n0 + lane8*8;
  u16* xbp = xb + (size_t)b*CH*NSP + n0 + lane8*8;
  #pragma unroll
  for (int p = 0; p < 8; ++p) {
    const int c = rq + p*32;                 // 0..255
    float4 v0 = *(const float4*)(xp + (size_t)c*NSP);
    float4 v1 = *(const float4*)(xp + (size_t)c*NSP + 4);
    float ps = v0.x+v0.y+v0.z+v0.w + v1.x+v1.y+v1.z+v1.w;
    #pragma unroll
    for (int o = 1; o < 8; o <<= 1) ps += __shfl_xor(ps, o, 64);
    if (lane8 == 0) psum[((size_t)b*64 + blockIdx.x)*CH + c] = ps;
    bf16x8 bv;
    bv[0]=(short)f2b(v0.x); bv[1]=(short)f2b(v0.y); bv[2]=(short)f2b(v0.z); bv[3]=(short)f2b(v0.w);
    bv[4]=(short)f2b(v1.x); bv[5]=(short)f2b(v1.y); bv[6]=(short)f2b(v1.z); bv[7]=(short)f2b(v1.w);
    *(bf16x8*)(xbp + (size_t)c*NSP) = bv;
    const int cs = c ^ (lane8 << 3);         // key: n>>3 = lane8 for all 8 elems
    #pragma unroll
    for (int j = 0; j < 8; ++j)
      sm.tl[(lane8*8 + j)*256 + cs] = (u16)bv[j];
  }
  __syncthreads();
  const int c8 = t & 31, nl = t >> 5;        // c8: 8-col group, nl 0..7
  u16* dst = xt + ((size_t)b*NSP + n0)*CH;
  #pragma unroll
  for (int p2 = 0; p2 < 8; ++p2) {
    const int n = p2*8 + nl;                 // n>>3 = p2 (uniform per instr)
    bf16x8 v = *(const bf16x8*)(sm.tl + n*256 + ((c8*8) ^ (p2 << 3)));
    *(bf16x8*)(dst + (size_t)n*CH + c8*8) = v;
  }
}

// ---------------- kernel 2: Gram partials, 64x64 symmetric tiles (10 of 16), KC=4
__global__ __launch_bounds__(256) void k_gram(const u16* __restrict__ xb, float* __restrict__ Sp) {
  __shared__ u16 As[64*64];   // 8 KB
  __shared__ u16 Bs[64*64];   // 8 KB
  const int TIa[10] = {0,0,0,0,1,1,1,2,2,3};
  const int TJa[10] = {0,1,2,3,1,2,3,2,3,3};
  const int L = blockIdx.x;
  const int wk = (L & 7) * 80 + (L >> 3);   // bijective: 640 = 8*80
  const int b = wk / 40;
  const int rem = wk % 40;
  const int kc = rem / 10;
  const int tile = rem % 10;
  const int ti = TIa[tile], tj = TJa[tile];
  const int m_base = ti*64, n_base = tj*64;
  const bool diag = (ti == tj);
  const int t = threadIdx.x, wv = t >> 6, l = t & 63;
  const int wr = wv >> 1, wc = wv & 1;
  const int lr = l & 15, lkb = l >> 4;      // fragment row lane, k sub-block
  const int sr8 = l >> 3, ss = l & 7;       // staging: row-within-8, 16B slot
  const u16* xa = xb + (size_t)b*CH*NSP;
  const int kbeg = kc * (NSP/KC);
  f32x4 acc[2][2];
  #pragma unroll
  for (int i = 0; i < 2; ++i)
    #pragma unroll
    for (int j = 0; j < 2; ++j) acc[i][j] = (f32x4){0.f,0.f,0.f,0.f};

  for (int kk = 0; kk < 16; ++kk) {
    const int kpos = kbeg + kk*64;
    #pragma unroll
    for (int j = 0; j < 2; ++j) {
      const int g = wv*2 + j;               // 0..7
      const int r = g*8 + sr8;              // 0..63
      async16(&As[g*512], xa + (size_t)(m_base + r)*NSP + kpos + ((ss ^ (r & 7)) * 8));
    }
    if (!diag) {
      #pragma unroll
      for (int j = 0; j < 2; ++j) {
        const int g = wv*2 + j;
        const int r = g*8 + sr8;
        async16(&Bs[g*512], xa + (size_t)(n_base + r)*NSP + kpos + ((ss ^ (r & 7)) * 8));
      }
    }
    __syncthreads();
    const u16* bsrc = diag ? As : Bs;
    #pragma unroll
    for (int ks = 0; ks < 2; ++ks) {
      bf16x8 A[2], Bf[2];
      #pragma unroll
      for (int mt = 0; mt < 2; ++mt) {
        const int ra = wr*32 + mt*16 + lr;
        A[mt] = *(const bf16x8*)(As + ra*64 + (((ks*4 + lkb) ^ (ra & 7)) * 8));
      }
      #pragma unroll
      for (int nt = 0; nt < 2; ++nt) {
        const int rb = wc*32 + nt*16 + lr;
        Bf[nt] = *(const bf16x8*)(bsrc + rb*64 + (((ks*4 + lkb) ^ (rb & 7)) * 8));
      }
      #pragma unroll
      for (int mt = 0; mt < 2; ++mt)
        #pragma unroll
        for (int nt = 0; nt < 2; ++nt)
          acc[mt][nt] = __builtin_amdgcn_mfma_f32_16x16x32_bf16(A[mt], Bf[nt], acc[mt][nt], 0, 0, 0);
    }
    __syncthreads();
  }
  float* Sb = Sp + (size_t)((b*KC + kc)*10 + tile)*4096;
  const int r0 = (l >> 4) * 4;
  #pragma unroll
  for (int mt = 0; mt < 2; ++mt)
    #pragma unroll
    for (int nt = 0; nt < 2; ++nt)
      #pragma unroll
      for (int rr = 0; rr < 4; ++rr) {
        const int lm = wr*32 + mt*16 + r0 + rr;
        const int lc = wc*32 + nt*16 + lr;
        Sb[lm*64 + lc] = acc[mt][nt][rr];
      }
}

// ---------------- fused: reduce Sp tiles -> S (with symmetric mirror) + per-batch vectors
__global__ __launch_bounds__(256) void k_redvec(const float* __restrict__ Sp,
    const float* __restrict__ psum, const float* __restrict__ E,
    const float* __restrict__ KT, const float* __restrict__ q,
    float* __restrict__ S, float* __restrict__ KS, float* __restrict__ Es,
    float* __restrict__ qs) {
  __shared__ float tl[64*65 + 8];
  const int b = blockIdx.y, xx = blockIdx.x, t = threadIdx.x;
  if (xx < 10) {
    const int TIa[10] = {0,0,0,0,1,1,1,2,2,3};
    const int TJa[10] = {0,1,2,3,1,2,3,2,3,3};
    const int ti = TIa[xx], tj = TJa[xx];
    const int row0 = ti*64, col0 = tj*64;
    float* Sb = S + (size_t)b*CH*CH;
    float4 sum[4];
    #pragma unroll
    for (int k = 0; k < 4; ++k) {
      const int slot = t + k*256;
      const int r = slot >> 4, c4 = (slot & 15) * 4;
      float4 s = {0.f,0.f,0.f,0.f};
      #pragma unroll
      for (int kc = 0; kc < KC; ++kc) {
        const float* p = Sp + (size_t)((b*KC + kc)*10 + xx)*4096;
        float4 v = *(const float4*)(p + r*64 + c4);
        s.x += v.x; s.y += v.y; s.z += v.z; s.w += v.w;
      }
      sum[k] = s;
      *(float4*)(Sb + (size_t)(row0 + r)*CH + col0 + c4) = s;
    }
    if (ti != tj) {                            // mirror to lower triangle
      #pragma unroll
      for (int k = 0; k < 4; ++k) {
        const int slot = t + k*256;
        const int r = slot >> 4, c4 = (slot & 15) * 4;
        tl[r*65 + c4+0] = sum[k].x; tl[r*65 + c4+1] = sum[k].y;
        tl[r*65 + c4+2] = sum[k].z; tl[r*65 + c4+3] = sum[k].w;
      }
      __syncthreads();
      #pragma unroll
      for (int k = 0; k < 4; ++k) {
        const int slot = t + k*256;
        const int r = slot >> 4, c4 = (slot & 15) * 4;
        float4 v = { tl[(c4+0)*65 + r], tl[(c4+1)*65 + r],
                     tl[(c4+2)*65 + r], tl[(c4+3)*65 + r] };
        *(float4*)(Sb + (size_t)(col0 + r)*CH + row0 + c4) = v;
      }
    }
  } else {
    float s = 0.f;
    for (int nb = 0; nb < 64; ++nb) s += psum[((size_t)b*64 + nb)*CH + t];
    tl[t] = s;
    __syncthreads();
    float ks = 0.f;
    for (int a = 0; a < CH; ++a) ks += KT[(size_t)a*CH + t] * tl[a];
    KS[(size_t)b*CH + t] = ks;
    float es = 0.f;
    for (int c = 0; c < CH; ++c) es += E[(size_t)t*CH + c] * tl[c];
    Es[(size_t)b*CH + t] = es;
    float p = q[t] * tl[t];
    #pragma unroll
    for (int o = 1; o < 64; o <<= 1) p += __shfl_xor(p, o, 64);
    if ((t & 63) == 0) tl[4160 + (t >> 6)] = p;
    __syncthreads();
    if (t == 0) qs[b] = tl[4160] + tl[4161] + tl[4162] + tl[4163];
  }
}

// ---------------- k_RP: fused R = E·S (LDS-resident) then P = (inv/N)(R·KT + rank1s) + I
__global__ __launch_bounds__(256) void k_RP(const float* __restrict__ S,
    const float* __restrict__ E, const float* __restrict__ KT,
    const float* __restrict__ q, const float* __restrict__ KS,
    const float* __restrict__ Es, const float* __restrict__ qs,
    const float* __restrict__ wg, const float* __restrict__ tphi,
    const float* __restrict__ inv, const float* __restrict__ dconst,
    const float* __restrict__ tb, u16* __restrict__ Pb, float* __restrict__ dv) {
  __shared__ float lEt[2048];
  __shared__ float lRt[2048];
  __shared__ float red[32];
  const int b = blockIdx.y, o0 = blockIdx.x*8, t = threadIdx.x;
  #pragma unroll
  for (int k = 0; k < 8; ++k) { int idx = k*256 + t;
    lEt[idx] = E[(size_t)(o0 + (idx & 7))*CH + (idx >> 3)]; }
  __syncthreads();
  const float* Sb = S + (size_t)b*CH*CH;
  float acc[8] = {0.f};
  for (int c = 0; c < CH; ++c) {
    float sv = Sb[(size_t)c*CH + t];
    #pragma unroll
    for (int r = 0; r < 8; ++r) acc[r] += lEt[c*8 + r] * sv;
  }
  #pragma unroll
  for (int r = 0; r < 8; ++r) lRt[t*8 + r] = acc[r];
  const float qt = q[t];
  #pragma unroll
  for (int r = 0; r < 8; ++r) {
    float p = acc[r] * qt;
    #pragma unroll
    for (int o = 1; o < 64; o <<= 1) p += __shfl_xor(p, o, 64);
    if ((t & 63) == 0) red[r*4 + (t >> 6)] = p;
  }
  __syncthreads();
  float acc2[8] = {0.f};
  for (int a = 0; a < CH; ++a) {
    float kv = KT[(size_t)a*CH + t];
    #pragma unroll
    for (int r = 0; r < 8; ++r) acc2[r] += lRt[a*8 + r] * kv;
  }
  const float ksv = KS[(size_t)b*CH + t], tpv = tphi[t];
  u16* Pbb = Pb + (size_t)b*CH*CH;
  #pragma unroll
  for (int r = 0; r < 8; ++r) {
    int o = o0 + r;
    float val = (acc2[r] + wg[o]*ksv + (Es[(size_t)b*CH + o] + (float)NSP*wg[o])*tpv)
                * inv[o] * (1.f/(float)NSP);
    if (o == t) val += 1.f;      // fold residual: P + I
    Pbb[(size_t)o*CH + t] = f2b(val);
  }
  if (t < 8) {
    int o = o0 + t;
    float iv = inv[o], wgo = wg[o], tb0 = tb[0];
    float rq = red[t*4] + red[t*4+1] + red[t*4+2] + red[t*4+3];
    float t2 = rq + wgo*qs[b] + Es[(size_t)b*CH + o]*tb0;
    dv[(size_t)b*CH + o] = iv*(t2*(1.f/(float)NSP) + wgo*tb0) + dconst[o];
  }
}

// ---------------- apply: out = (P+I) X + d 1^T  (LDS-staged B, coalesced f32 epilogue)
__global__ __launch_bounds__(512, 4) void k_apply(const u16* __restrict__ Pb,
    const u16* __restrict__ xt, const float* __restrict__ dv,
    float* __restrict__ out) {
  __shared__ union {
    u16   bx[64*256];        // 32 KB bf16 B-tile (XOR-swizzled 16B slots)
    float fe[8][16][68];     // 34 KB per-wave f32 epilogue buffers (stride 68)
  } sm;
  const int b = blockIdx.y, n0 = blockIdx.x*64;
  const int t = threadIdx.x, w = t >> 6, l = t & 63;
  {
    const u16* src = xt + ((size_t)b*NSP + n0)*CH;
    const int r = t >> 3, sbase = t & 7;
    #pragma unroll
    for (int it = 0; it < 4; ++it) {
      int slot = sbase + it*8;         // 0..31 (16B slots within 512B row)
      bf16x8 v = *(const bf16x8*)(src + (size_t)r*CH + slot*8);
      *(bf16x8*)(sm.bx + r*256 + ((slot ^ (r & 7)) * 8)) = v;
    }
  }
  __syncthreads();
  const int m0 = w*32;
  const int lr = l & 15, lkb = l >> 4;   // k sub-block 0..3 (8 elems each)
  const int sw = lr & 7;
  const u16* Pp = Pb + (size_t)b*CH*CH;
  f32x4 acc[2][4];
  #pragma unroll
  for (int i = 0; i < 2; ++i)
    #pragma unroll
    for (int j = 0; j < 4; ++j) acc[i][j] = (f32x4){0.f,0.f,0.f,0.f};
  #pragma unroll
  for (int kk = 0; kk < 8; ++kk) {
    bf16x8 A[2], Bf[4];
    #pragma unroll
    for (int mt = 0; mt < 2; ++mt)
      A[mt] = *(const bf16x8*)(Pp + (size_t)(m0 + mt*16 + lr)*CH + kk*32 + lkb*8);
    #pragma unroll
    for (int nt = 0; nt < 4; ++nt) {
      int slot = kk*4 + lkb;
      Bf[nt] = *(const bf16x8*)(sm.bx + (nt*16 + lr)*256 + ((slot ^ sw) * 8));
    }
    #pragma unroll
    for (int mt = 0; mt < 2; ++mt)
      #pragma unroll
      for (int nt = 0; nt < 4; ++nt)
        acc[mt][nt] = __builtin_amdgcn_mfma_f32_16x16x32_bf16(A[mt], Bf[nt], acc[mt][nt], 0, 0, 0);
  }
  __syncthreads();                     // B-tile dead; reuse LDS for epilogue
  float* ob = out + (size_t)b*CH*NSP;
  const int r0 = (l >> 4) * 4;
  #pragma unroll
  for (int mt = 0; mt < 2; ++mt) {
    #pragma unroll
    for (int rr = 0; rr < 4; ++rr) {
      float dval = dv[(size_t)b*CH + m0 + mt*16 + r0 + rr];
      #pragma unroll
      for (int nt = 0; nt < 4; ++nt)
        sm.fe[w][r0 + rr][nt*16 + lr] = acc[mt][nt][rr] + dval;
    }
    #pragma unroll
    for (int i = 0; i < 4; ++i) {
      int s = l + 64*i;
      int rrow = s >> 4, c4 = (s & 15) * 4;
      float4 v = *(const float4*)&sm.fe[w][rrow][c4];
      *(float4*)&ob[(size_t)(m0 + mt*16 + rrow)*NSP + n0 + c4] = v;
    }
  }
}

// ---------------- workspace layout (bytes)
static constexpr size_t XT_OFF = 0;              // bf16 [16][4096][256]  33,554,432
static constexpr size_t S_OFF  = 33554432;       // f32  [16][256][256]    4,194,304
static constexpr size_t PB_OFF = 37748736;       // bf16 [16][256][256]    2,097,152
static constexpr size_t PS_OFF = 39845888;       // f32  [16][64][256]     1,048,576
static constexpr size_t E_OFF  = 40894464;       // f32  [256][256]          262,144
static constexpr size_t KT_OFF = 41156608;       // f32  [256][256]          262,144
static constexpr size_t WG_OFF = 41418752;       // f32 [256] (1K pad each follows)
static constexpr size_t TP_OFF = 41419776;
static constexpr size_t QV_OFF = 41420800;
static constexpr size_t IV_OFF = 41421824;
static constexpr size_t DC_OFF = 41422848;
static constexpr size_t TB_OFF = 41423872;
static constexpr size_t KS_OFF = 41424896;       // f32 [16][256] 16,384
static constexpr size_t ES_OFF = 41441280;       // f32 [16][256] 16,384
static constexpr size_t QS_OFF = 41457664;       // f32 [16] (1K pad)
static constexpr size_t DV_OFF = 41458688;       // f32 [16][256] 16,384

extern "C" void kernel_launch(void* const* d_in, const int* in_sizes, int n_in,
                              void* d_out, int out_size, void* d_ws, size_t ws_size,
                              hipStream_t stream) {
  const float* x       = (const float*)d_in[0];
  const float* g_w     = (const float*)d_in[1];
  const float* g_b     = (const float*)d_in[2];
  const float* theta_w = (const float*)d_in[3];
  const float* theta_b = (const float*)d_in[4];
  const float* phi_w   = (const float*)d_in[5];
  const float* phi_b   = (const float*)d_in[6];
  const float* w_w     = (const float*)d_in[7];
  const float* w_b     = (const float*)d_in[8];
  const float* bn_g    = (const float*)d_in[9];
  const float* bn_b    = (const float*)d_in[10];
  const float* bn_m    = (const float*)d_in[11];
  const float* bn_v    = (const float*)d_in[12];
  float* out = (float*)d_out;
  char* ws = (char*)d_ws;
  u16*   XT = (u16*)(ws + XT_OFF);
  float* S  = (float*)(ws + S_OFF);
  u16*   Pb = (u16*)(ws + PB_OFF);
  float* PS = (float*)(ws + PS_OFF);
  float* E  = (float*)(ws + E_OFF);
  float* KT = (float*)(ws + KT_OFF);
  float* WG = (float*)(ws + WG_OFF);
  float* TP = (float*)(ws + TP_OFF);
  float* QV = (float*)(ws + QV_OFF);
  float* IV = (float*)(ws + IV_OFF);
  float* DC = (float*)(ws + DC_OFF);
  float* TB = (float*)(ws + TB_OFF);
  float* KS = (float*)(ws + KS_OFF);
  float* ES = (float*)(ws + ES_OFF);
  float* QS = (float*)(ws + QS_OFF);
  float* DV = (float*)(ws + DV_OFF);
  // d_out scratch: Xb bf16 [0, 33.5MB); compact Sp [33.5MB, +10.5MB). Dead before k_apply.
  u16*   Xb = (u16*)d_out;
  float* Sp = (float*)((char*)d_out + 33554432);

  k_prep  <<<dim3(65, 1, BATCH+1),        256, 0, stream>>>(x, Xb, XT, PS,
            w_w, g_w, g_b, theta_w, theta_b, phi_w, phi_b, w_b, bn_g, bn_b, bn_m, bn_v,
            E, KT, WG, TP, QV, IV, DC, TB);
  k_gram  <<<dim3(640),                   256, 0, stream>>>(Xb, Sp);
  k_redvec<<<dim3(11, BATCH),             256, 0, stream>>>(Sp, PS, E, KT, QV, S, KS, ES, QS);
  k_RP    <<<dim3(32, BATCH),             256, 0, stream>>>(S, E, KT, QV, KS, ES, QS, WG, TP, IV, DC, TB, Pb, DV);
  k_apply <<<dim3(NSP/64, BATCH),         512, 0, stream>>>(Pb, XT, DV, out);
}

// Round 12
// 117.983 us; speedup vs baseline: 1.0928x; 1.0188x over previous
//
#include <hip/hip_runtime.h>
#include <stdint.h>

#define BATCH 16
#define CH    256
#define CI    128
#define NSP   4096
#define KC    4          // K-split chunks for the Gram GEMM
#define EPSV  1e-5f

typedef unsigned short u16;
typedef __attribute__((ext_vector_type(4))) float f32x4;
typedef __attribute__((ext_vector_type(8))) short bf16x8;

__device__ __forceinline__ u16 f2b(float f) {
  uint32_t u = __float_as_uint(f);
  uint32_t r = u + 0x7FFFu + ((u >> 16) & 1u);   // round-to-nearest-even
  return (u16)(r >> 16);
}

__device__ __forceinline__ void async16(void* lds, const void* g) {
  __builtin_amdgcn_global_load_lds(
      (const __attribute__((address_space(1))) unsigned int*)g,
      (__attribute__((address_space(3))) unsigned int*)lds, 16, 0, 0);
}

// ---------------- k_prep: pure stream — x f32 -> Xb bf16 (16B stores) + psum.
// grid (64, 4, 17): z<16 = batch slices (R10-verified body); z==16 = const roles.
__global__ __launch_bounds__(256) void k_prep(const float* __restrict__ x,
    u16* __restrict__ xb, float* __restrict__ psum,
    const float* __restrict__ w_w, const float* __restrict__ g_w,
    const float* __restrict__ g_b, const float* __restrict__ theta_w,
    const float* __restrict__ theta_b, const float* __restrict__ phi_w,
    const float* __restrict__ phi_b, const float* __restrict__ w_b,
    const float* __restrict__ bn_g, const float* __restrict__ bn_b,
    const float* __restrict__ bn_m, const float* __restrict__ bn_v,
    float* __restrict__ E, float* __restrict__ KT, float* __restrict__ wg,
    float* __restrict__ tphi, float* __restrict__ q, float* __restrict__ inv,
    float* __restrict__ dconst, float* __restrict__ tb) {
  __shared__ float lbuf[1024];
  const int t = threadIdx.x;
  if (blockIdx.z == BATCH) {                 // ---- const role (verified body)
    const int id = blockIdx.y*64 + blockIdx.x;
    if (id < 32) {
      const int o0 = id*8;
      #pragma unroll
      for (int k = 0; k < 4; ++k) { int idx = k*256 + t;
        lbuf[idx] = w_w[(size_t)(o0 + (idx & 7))*CI + (idx >> 3)]; }
      __syncthreads();
      float acc[8] = {0.f};
      for (int j = 0; j < CI; ++j) {
        float gv = g_w[(size_t)j*CH + t];
        #pragma unroll
        for (int r = 0; r < 8; ++r) acc[r] += lbuf[j*8 + r] * gv;
      }
      #pragma unroll
      for (int r = 0; r < 8; ++r) E[(size_t)(o0 + r)*CH + t] = acc[r];
    } else if (id < 64) {
      const int a0 = (id - 32)*8;
      #pragma unroll
      for (int k = 0; k < 4; ++k) { int idx = k*256 + t;
        lbuf[idx] = phi_w[(size_t)(idx >> 3)*CH + a0 + (idx & 7)]; }
      __syncthreads();
      float acc[8] = {0.f};
      for (int i = 0; i < CI; ++i) {
        float tv = theta_w[(size_t)i*CH + t];
        #pragma unroll
        for (int u = 0; u < 8; ++u) acc[u] += lbuf[i*8 + u] * tv;
      }
      #pragma unroll
      for (int u = 0; u < 8; ++u) KT[(size_t)(a0 + u)*CH + t] = acc[u];
    } else if (id == 64) {
      float iv = bn_g[t] * rsqrtf(bn_v[t] + EPSV);
      inv[t] = iv;
      dconst[t] = iv*w_b[t] + bn_b[t] - bn_m[t]*iv;
      float a = 0.f;
      for (int j = 0; j < CI; ++j) a += w_w[(size_t)t*CI + j] * g_b[j];
      wg[t] = a;
      float tp = 0.f, qq = 0.f;
      for (int i = 0; i < CI; ++i) {
        tp += theta_w[(size_t)i*CH + t] * phi_b[i];
        qq += phi_w[(size_t)i*CH + t] * theta_b[i];
      }
      tphi[t] = tp; q[t] = qq;
      lbuf[t] = (t < CI) ? theta_b[t]*phi_b[t] : 0.f;
      __syncthreads();
      for (int s2 = 128; s2 > 0; s2 >>= 1) { if (t < s2) lbuf[t] += lbuf[t + s2]; __syncthreads(); }
      if (t == 0) tb[0] = lbuf[0];
    }
    return;
  }
  // ---- streaming role: 64c x 64n tile, no LDS, no barriers (R10-verified)
  const int b = blockIdx.z, c0 = blockIdx.y*64, n0 = blockIdx.x*64;
  const int lane8 = t & 7, rq = t >> 3;        // rq 0..31
  const float* xp = x + ((size_t)b*CH + c0)*NSP + n0 + lane8*8;
  u16* xbp = xb + ((size_t)b*CH + c0)*NSP + n0 + lane8*8;
  #pragma unroll
  for (int p = 0; p < 2; ++p) {
    const int cl = rq + p*32;
    float4 v0 = *(const float4*)(xp + (size_t)cl*NSP);
    float4 v1 = *(const float4*)(xp + (size_t)cl*NSP + 4);
    float ps = v0.x+v0.y+v0.z+v0.w + v1.x+v1.y+v1.z+v1.w;
    #pragma unroll
    for (int o = 1; o < 8; o <<= 1) ps += __shfl_xor(ps, o, 64);
    if (lane8 == 0) psum[((size_t)b*64 + blockIdx.x)*CH + c0 + cl] = ps;
    bf16x8 bv;
    bv[0]=(short)f2b(v0.x); bv[1]=(short)f2b(v0.y); bv[2]=(short)f2b(v0.z); bv[3]=(short)f2b(v0.w);
    bv[4]=(short)f2b(v1.x); bv[5]=(short)f2b(v1.y); bv[6]=(short)f2b(v1.z); bv[7]=(short)f2b(v1.w);
    *(bf16x8*)(xbp + (size_t)cl*NSP) = bv;
  }
}

// ---------------- kernel 2: Gram partials, 64x64 symmetric tiles (10 of 16), KC=4
__global__ __launch_bounds__(256) void k_gram(const u16* __restrict__ xb, float* __restrict__ Sp) {
  __shared__ u16 As[64*64];   // 8 KB
  __shared__ u16 Bs[64*64];   // 8 KB
  const int TIa[10] = {0,0,0,0,1,1,1,2,2,3};
  const int TJa[10] = {0,1,2,3,1,2,3,2,3,3};
  const int L = blockIdx.x;
  const int wk = (L & 7) * 80 + (L >> 3);   // bijective: 640 = 8*80
  const int b = wk / 40;
  const int rem = wk % 40;
  const int kc = rem / 10;
  const int tile = rem % 10;
  const int ti = TIa[tile], tj = TJa[tile];
  const int m_base = ti*64, n_base = tj*64;
  const bool diag = (ti == tj);
  const int t = threadIdx.x, wv = t >> 6, l = t & 63;
  const int wr = wv >> 1, wc = wv & 1;
  const int lr = l & 15, lkb = l >> 4;      // fragment row lane, k sub-block
  const int sr8 = l >> 3, ss = l & 7;       // staging: row-within-8, 16B slot
  const u16* xa = xb + (size_t)b*CH*NSP;
  const int kbeg = kc * (NSP/KC);
  f32x4 acc[2][2];
  #pragma unroll
  for (int i = 0; i < 2; ++i)
    #pragma unroll
    for (int j = 0; j < 2; ++j) acc[i][j] = (f32x4){0.f,0.f,0.f,0.f};

  for (int kk = 0; kk < 16; ++kk) {
    const int kpos = kbeg + kk*64;
    #pragma unroll
    for (int j = 0; j < 2; ++j) {
      const int g = wv*2 + j;               // 0..7
      const int r = g*8 + sr8;              // 0..63
      async16(&As[g*512], xa + (size_t)(m_base + r)*NSP + kpos + ((ss ^ (r & 7)) * 8));
    }
    if (!diag) {
      #pragma unroll
      for (int j = 0; j < 2; ++j) {
        const int g = wv*2 + j;
        const int r = g*8 + sr8;
        async16(&Bs[g*512], xa + (size_t)(n_base + r)*NSP + kpos + ((ss ^ (r & 7)) * 8));
      }
    }
    __syncthreads();
    const u16* bsrc = diag ? As : Bs;
    #pragma unroll
    for (int ks = 0; ks < 2; ++ks) {
      bf16x8 A[2], Bf[2];
      #pragma unroll
      for (int mt = 0; mt < 2; ++mt) {
        const int ra = wr*32 + mt*16 + lr;
        A[mt] = *(const bf16x8*)(As + ra*64 + (((ks*4 + lkb) ^ (ra & 7)) * 8));
      }
      #pragma unroll
      for (int nt = 0; nt < 2; ++nt) {
        const int rb = wc*32 + nt*16 + lr;
        Bf[nt] = *(const bf16x8*)(bsrc + rb*64 + (((ks*4 + lkb) ^ (rb & 7)) * 8));
      }
      #pragma unroll
      for (int mt = 0; mt < 2; ++mt)
        #pragma unroll
        for (int nt = 0; nt < 2; ++nt)
          acc[mt][nt] = __builtin_amdgcn_mfma_f32_16x16x32_bf16(A[mt], Bf[nt], acc[mt][nt], 0, 0, 0);
    }
    __syncthreads();
  }
  float* Sb = Sp + (size_t)((b*KC + kc)*10 + tile)*4096;
  const int r0 = (l >> 4) * 4;
  #pragma unroll
  for (int mt = 0; mt < 2; ++mt)
    #pragma unroll
    for (int nt = 0; nt < 2; ++nt)
      #pragma unroll
      for (int rr = 0; rr < 4; ++rr) {
        const int lm = wr*32 + mt*16 + r0 + rr;
        const int lc = wc*32 + nt*16 + lr;
        Sb[lm*64 + lc] = acc[mt][nt][rr];
      }
}

// ---------------- fused: reduce Sp tiles -> S (with symmetric mirror) + per-batch vectors
__global__ __launch_bounds__(256) void k_redvec(const float* __restrict__ Sp,
    const float* __restrict__ psum, const float* __restrict__ E,
    const float* __restrict__ KT, const float* __restrict__ q,
    float* __restrict__ S, float* __restrict__ KS, float* __restrict__ Es,
    float* __restrict__ qs) {
  __shared__ float tl[64*65 + 8];
  const int b = blockIdx.y, xx = blockIdx.x, t = threadIdx.x;
  if (xx < 10) {
    const int TIa[10] = {0,0,0,0,1,1,1,2,2,3};
    const int TJa[10] = {0,1,2,3,1,2,3,2,3,3};
    const int ti = TIa[xx], tj = TJa[xx];
    const int row0 = ti*64, col0 = tj*64;
    float* Sb = S + (size_t)b*CH*CH;
    float4 sum[4];
    #pragma unroll
    for (int k = 0; k < 4; ++k) {
      const int slot = t + k*256;
      const int r = slot >> 4, c4 = (slot & 15) * 4;
      float4 s = {0.f,0.f,0.f,0.f};
      #pragma unroll
      for (int kc = 0; kc < KC; ++kc) {
        const float* p = Sp + (size_t)((b*KC + kc)*10 + xx)*4096;
        float4 v = *(const float4*)(p + r*64 + c4);
        s.x += v.x; s.y += v.y; s.z += v.z; s.w += v.w;
      }
      sum[k] = s;
      *(float4*)(Sb + (size_t)(row0 + r)*CH + col0 + c4) = s;
    }
    if (ti != tj) {                            // mirror to lower triangle
      #pragma unroll
      for (int k = 0; k < 4; ++k) {
        const int slot = t + k*256;
        const int r = slot >> 4, c4 = (slot & 15) * 4;
        tl[r*65 + c4+0] = sum[k].x; tl[r*65 + c4+1] = sum[k].y;
        tl[r*65 + c4+2] = sum[k].z; tl[r*65 + c4+3] = sum[k].w;
      }
      __syncthreads();
      #pragma unroll
      for (int k = 0; k < 4; ++k) {
        const int slot = t + k*256;
        const int r = slot >> 4, c4 = (slot & 15) * 4;
        float4 v = { tl[(c4+0)*65 + r], tl[(c4+1)*65 + r],
                     tl[(c4+2)*65 + r], tl[(c4+3)*65 + r] };
        *(float4*)(Sb + (size_t)(col0 + r)*CH + row0 + c4) = v;
      }
    }
  } else {
    float s = 0.f;
    for (int nb = 0; nb < 64; ++nb) s += psum[((size_t)b*64 + nb)*CH + t];
    tl[t] = s;
    __syncthreads();
    float ks = 0.f;
    for (int a = 0; a < CH; ++a) ks += KT[(size_t)a*CH + t] * tl[a];
    KS[(size_t)b*CH + t] = ks;
    float es = 0.f;
    for (int c = 0; c < CH; ++c) es += E[(size_t)t*CH + c] * tl[c];
    Es[(size_t)b*CH + t] = es;
    float p = q[t] * tl[t];
    #pragma unroll
    for (int o = 1; o < 64; o <<= 1) p += __shfl_xor(p, o, 64);
    if ((t & 63) == 0) tl[4160 + (t >> 6)] = p;
    __syncthreads();
    if (t == 0) qs[b] = tl[4160] + tl[4161] + tl[4162] + tl[4163];
  }
}

// ---------------- k_RP: fused R = E·S (LDS-resident) then P = (inv/N)(R·KT + rank1s) + I
__global__ __launch_bounds__(256) void k_RP(const float* __restrict__ S,
    const float* __restrict__ E, const float* __restrict__ KT,
    const float* __restrict__ q, const float* __restrict__ KS,
    const float* __restrict__ Es, const float* __restrict__ qs,
    const float* __restrict__ wg, const float* __restrict__ tphi,
    const float* __restrict__ inv, const float* __restrict__ dconst,
    const float* __restrict__ tb, u16* __restrict__ Pb, float* __restrict__ dv) {
  __shared__ float lEt[2048];
  __shared__ float lRt[2048];
  __shared__ float red[32];
  const int b = blockIdx.y, o0 = blockIdx.x*8, t = threadIdx.x;
  #pragma unroll
  for (int k = 0; k < 8; ++k) { int idx = k*256 + t;
    lEt[idx] = E[(size_t)(o0 + (idx & 7))*CH + (idx >> 3)]; }
  __syncthreads();
  const float* Sb = S + (size_t)b*CH*CH;
  float acc[8] = {0.f};
  for (int c = 0; c < CH; ++c) {
    float sv = Sb[(size_t)c*CH + t];
    #pragma unroll
    for (int r = 0; r < 8; ++r) acc[r] += lEt[c*8 + r] * sv;
  }
  #pragma unroll
  for (int r = 0; r < 8; ++r) lRt[t*8 + r] = acc[r];
  const float qt = q[t];
  #pragma unroll
  for (int r = 0; r < 8; ++r) {
    float p = acc[r] * qt;
    #pragma unroll
    for (int o = 1; o < 64; o <<= 1) p += __shfl_xor(p, o, 64);
    if ((t & 63) == 0) red[r*4 + (t >> 6)] = p;
  }
  __syncthreads();
  float acc2[8] = {0.f};
  for (int a = 0; a < CH; ++a) {
    float kv = KT[(size_t)a*CH + t];
    #pragma unroll
    for (int r = 0; r < 8; ++r) acc2[r] += lRt[a*8 + r] * kv;
  }
  const float ksv = KS[(size_t)b*CH + t], tpv = tphi[t];
  u16* Pbb = Pb + (size_t)b*CH*CH;
  #pragma unroll
  for (int r = 0; r < 8; ++r) {
    int o = o0 + r;
    float val = (acc2[r] + wg[o]*ksv + (Es[(size_t)b*CH + o] + (float)NSP*wg[o])*tpv)
                * inv[o] * (1.f/(float)NSP);
    if (o == t) val += 1.f;      // fold residual: P + I
    Pbb[(size_t)o*CH + t] = f2b(val);
  }
  if (t < 8) {
    int o = o0 + t;
    float iv = inv[o], wgo = wg[o], tb0 = tb[0];
    float rq = red[t*4] + red[t*4+1] + red[t*4+2] + red[t*4+3];
    float t2 = rq + wgo*qs[b] + Es[(size_t)b*CH + o]*tb0;
    dv[(size_t)b*CH + o] = iv*(t2*(1.f/(float)NSP) + wgo*tb0) + dconst[o];
  }
}

// ---------------- apply: out = (P+I) X + d 1^T — stages Xb [c][n] and transposes
// in LDS via the verified scatter-store. Layout: tl[n*256 + (c ^ (K(n)<<3))],
// K(n) = (n&7) ^ (n>>3). Both store and MFMA-read spread to 2 lanes/bank (free).
// grid (NSP/64, BATCH), block 512 = 8 waves, wave tile 32 rows x 64 cols.
__global__ __launch_bounds__(512, 4) void k_apply(const u16* __restrict__ Pb,
    const u16* __restrict__ xb, const float* __restrict__ dv,
    float* __restrict__ out) {
  __shared__ union {
    u16   tl[64*256];        // 32 KB bf16 transposed tile (XOR-swizzled octets)
    float fe[8][16][68];     // 34 KB per-wave f32 epilogue buffers (stride 68)
  } sm;
  const int b = blockIdx.y, n0 = blockIdx.x*64;
  const int t = threadIdx.x, w = t >> 6, l = t & 63;
  {
    const u16* src = xb + (size_t)b*CH*NSP + n0;
    const int lane8 = t & 7, rq = t >> 3;      // rq 0..63
    #pragma unroll
    for (int p = 0; p < 4; ++p) {
      const int c = rq + p*64;                 // 0..255
      bf16x8 v = *(const bf16x8*)(src + (size_t)c*NSP + lane8*8);
      #pragma unroll
      for (int j = 0; j < 8; ++j) {
        const int K = j ^ lane8;               // K(n) with n = lane8*8+j
        sm.tl[(lane8*8 + j)*256 + (c ^ (K << 3))] = (u16)v[j];
      }
    }
  }
  __syncthreads();
  const int m0 = w*32;
  const int lr = l & 15, lkb = l >> 4;   // k sub-block 0..3 (8 elems each)
  const u16* Pp = Pb + (size_t)b*CH*CH;
  f32x4 acc[2][4];
  #pragma unroll
  for (int i = 0; i < 2; ++i)
    #pragma unroll
    for (int j = 0; j < 4; ++j) acc[i][j] = (f32x4){0.f,0.f,0.f,0.f};
  #pragma unroll
  for (int kk = 0; kk < 8; ++kk) {
    bf16x8 A[2], Bf[4];
    #pragma unroll
    for (int mt = 0; mt < 2; ++mt)
      A[mt] = *(const bf16x8*)(Pp + (size_t)(m0 + mt*16 + lr)*CH + kk*32 + lkb*8);
    #pragma unroll
    for (int nt = 0; nt < 4; ++nt) {
      const int row = nt*16 + lr;
      const int K = (row & 7) ^ (row >> 3);
      const int slot = kk*4 + lkb;
      Bf[nt] = *(const bf16x8*)(sm.tl + row*256 + ((slot ^ K) * 8));
    }
    #pragma unroll
    for (int mt = 0; mt < 2; ++mt)
      #pragma unroll
      for (int nt = 0; nt < 4; ++nt)
        acc[mt][nt] = __builtin_amdgcn_mfma_f32_16x16x32_bf16(A[mt], Bf[nt], acc[mt][nt], 0, 0, 0);
  }
  __syncthreads();                     // tile dead; reuse LDS for epilogue
  float* ob = out + (size_t)b*CH*NSP;
  const int r0 = (l >> 4) * 4;
  #pragma unroll
  for (int mt = 0; mt < 2; ++mt) {
    #pragma unroll
    for (int rr = 0; rr < 4; ++rr) {
      float dval = dv[(size_t)b*CH + m0 + mt*16 + r0 + rr];
      #pragma unroll
      for (int nt = 0; nt < 4; ++nt)
        sm.fe[w][r0 + rr][nt*16 + lr] = acc[mt][nt][rr] + dval;
    }
    #pragma unroll
    for (int i = 0; i < 4; ++i) {
      int s = l + 64*i;
      int rrow = s >> 4, c4 = (s & 15) * 4;
      float4 v = *(const float4*)&sm.fe[w][rrow][c4];
      *(float4*)&ob[(size_t)(m0 + mt*16 + rrow)*NSP + n0 + c4] = v;
    }
  }
}

// ---------------- workspace layout (bytes) — Xb now lives in ws (old XT slot)
static constexpr size_t XB_OFF = 0;              // bf16 [16][256][4096]  33,554,432
static constexpr size_t S_OFF  = 33554432;       // f32  [16][256][256]    4,194,304
static constexpr size_t PB_OFF = 37748736;       // bf16 [16][256][256]    2,097,152
static constexpr size_t PS_OFF = 39845888;       // f32  [16][64][256]     1,048,576
static constexpr size_t E_OFF  = 40894464;       // f32  [256][256]          262,144
static constexpr size_t KT_OFF = 41156608;       // f32  [256][256]          262,144
static constexpr size_t WG_OFF = 41418752;       // f32 [256] (1K pad each follows)
static constexpr size_t TP_OFF = 41419776;
static constexpr size_t QV_OFF = 41420800;
static constexpr size_t IV_OFF = 41421824;
static constexpr size_t DC_OFF = 41422848;
static constexpr size_t TB_OFF = 41423872;
static constexpr size_t KS_OFF = 41424896;       // f32 [16][256] 16,384
static constexpr size_t ES_OFF = 41441280;       // f32 [16][256] 16,384
static constexpr size_t QS_OFF = 41457664;       // f32 [16] (1K pad)
static constexpr size_t DV_OFF = 41458688;       // f32 [16][256] 16,384

extern "C" void kernel_launch(void* const* d_in, const int* in_sizes, int n_in,
                              void* d_out, int out_size, void* d_ws, size_t ws_size,
                              hipStream_t stream) {
  const float* x       = (const float*)d_in[0];
  const float* g_w     = (const float*)d_in[1];
  const float* g_b     = (const float*)d_in[2];
  const float* theta_w = (const float*)d_in[3];
  const float* theta_b = (const float*)d_in[4];
  const float* phi_w   = (const float*)d_in[5];
  const float* phi_b   = (const float*)d_in[6];
  const float* w_w     = (const float*)d_in[7];
  const float* w_b     = (const float*)d_in[8];
  const float* bn_g    = (const float*)d_in[9];
  const float* bn_b    = (const float*)d_in[10];
  const float* bn_m    = (const float*)d_in[11];
  const float* bn_v    = (const float*)d_in[12];
  float* out = (float*)d_out;
  char* ws = (char*)d_ws;
  u16*   Xb = (u16*)(ws + XB_OFF);
  float* S  = (float*)(ws + S_OFF);
  u16*   Pb = (u16*)(ws + PB_OFF);
  float* PS = (float*)(ws + PS_OFF);
  float* E  = (float*)(ws + E_OFF);
  float* KT = (float*)(ws + KT_OFF);
  float* WG = (float*)(ws + WG_OFF);
  float* TP = (float*)(ws + TP_OFF);
  float* QV = (float*)(ws + QV_OFF);
  float* IV = (float*)(ws + IV_OFF);
  float* DC = (float*)(ws + DC_OFF);
  float* TB = (float*)(ws + TB_OFF);
  float* KS = (float*)(ws + KS_OFF);
  float* ES = (float*)(ws + ES_OFF);
  float* QS = (float*)(ws + QS_OFF);
  float* DV = (float*)(ws + DV_OFF);
  // d_out scratch: compact Sp [33.5MB, +10.5MB). Dead before k_apply rewrites d_out.
  float* Sp = (float*)((char*)d_out + 33554432);

  k_prep  <<<dim3(64, 4, BATCH+1),        256, 0, stream>>>(x, Xb, PS,
            w_w, g_w, g_b, theta_w, theta_b, phi_w, phi_b, w_b, bn_g, bn_b, bn_m, bn_v,
            E, KT, WG, TP, QV, IV, DC, TB);
  k_gram  <<<dim3(640),                   256, 0, stream>>>(Xb, Sp);
  k_redvec<<<dim3(11, BATCH),             256, 0, stream>>>(Sp, PS, E, KT, QV, S, KS, ES, QS);
  k_RP    <<<dim3(32, BATCH),             256, 0, stream>>>(S, E, KT, QV, KS, ES, QS, WG, TP, IV, DC, TB, Pb, DV);
  k_apply <<<dim3(NSP/64, BATCH),         512, 0, stream>>>(Pb, Xb, DV, out);
}

// Round 13
// 117.831 us; speedup vs baseline: 1.0942x; 1.0013x over previous
//
#include <hip/hip_runtime.h>
#include <stdint.h>

#define BATCH 16
#define CH    256
#define CI    128
#define NSP   4096
#define KC    4          // K-split chunks for the Gram GEMM
#define EPSV  1e-5f

typedef unsigned short u16;
typedef __attribute__((ext_vector_type(4))) float f32x4;
typedef __attribute__((ext_vector_type(8))) short bf16x8;

__device__ __forceinline__ u16 f2b(float f) {
  uint32_t u = __float_as_uint(f);
  uint32_t r = u + 0x7FFFu + ((u >> 16) & 1u);   // round-to-nearest-even
  return (u16)(r >> 16);
}

__device__ __forceinline__ void async16(void* lds, const void* g) {
  __builtin_amdgcn_global_load_lds(
      (const __attribute__((address_space(1))) unsigned int*)g,
      (__attribute__((address_space(3))) unsigned int*)lds, 16, 0, 0);
}

// ---------------- k_prep: pure stream — x f32 -> Xb bf16 (16B stores) + psum.
// grid (64, 4, 17): z<16 = batch slices (R10-verified body); z==16 = const roles.
__global__ __launch_bounds__(256) void k_prep(const float* __restrict__ x,
    u16* __restrict__ xb, float* __restrict__ psum,
    const float* __restrict__ w_w, const float* __restrict__ g_w,
    const float* __restrict__ g_b, const float* __restrict__ theta_w,
    const float* __restrict__ theta_b, const float* __restrict__ phi_w,
    const float* __restrict__ phi_b, const float* __restrict__ w_b,
    const float* __restrict__ bn_g, const float* __restrict__ bn_b,
    const float* __restrict__ bn_m, const float* __restrict__ bn_v,
    float* __restrict__ E, float* __restrict__ KT, float* __restrict__ wg,
    float* __restrict__ tphi, float* __restrict__ q, float* __restrict__ inv,
    float* __restrict__ dconst, float* __restrict__ tb) {
  __shared__ float lbuf[1024];
  const int t = threadIdx.x;
  if (blockIdx.z == BATCH) {                 // ---- const role (verified body)
    const int id = blockIdx.y*64 + blockIdx.x;
    if (id < 32) {
      const int o0 = id*8;
      #pragma unroll
      for (int k = 0; k < 4; ++k) { int idx = k*256 + t;
        lbuf[idx] = w_w[(size_t)(o0 + (idx & 7))*CI + (idx >> 3)]; }
      __syncthreads();
      float acc[8] = {0.f};
      for (int j = 0; j < CI; ++j) {
        float gv = g_w[(size_t)j*CH + t];
        #pragma unroll
        for (int r = 0; r < 8; ++r) acc[r] += lbuf[j*8 + r] * gv;
      }
      #pragma unroll
      for (int r = 0; r < 8; ++r) E[(size_t)(o0 + r)*CH + t] = acc[r];
    } else if (id < 64) {
      const int a0 = (id - 32)*8;
      #pragma unroll
      for (int k = 0; k < 4; ++k) { int idx = k*256 + t;
        lbuf[idx] = phi_w[(size_t)(idx >> 3)*CH + a0 + (idx & 7)]; }
      __syncthreads();
      float acc[8] = {0.f};
      for (int i = 0; i < CI; ++i) {
        float tv = theta_w[(size_t)i*CH + t];
        #pragma unroll
        for (int u = 0; u < 8; ++u) acc[u] += lbuf[i*8 + u] * tv;
      }
      #pragma unroll
      for (int u = 0; u < 8; ++u) KT[(size_t)(a0 + u)*CH + t] = acc[u];
    } else if (id == 64) {
      float iv = bn_g[t] * rsqrtf(bn_v[t] + EPSV);
      inv[t] = iv;
      dconst[t] = iv*w_b[t] + bn_b[t] - bn_m[t]*iv;
      float a = 0.f;
      for (int j = 0; j < CI; ++j) a += w_w[(size_t)t*CI + j] * g_b[j];
      wg[t] = a;
      float tp = 0.f, qq = 0.f;
      for (int i = 0; i < CI; ++i) {
        tp += theta_w[(size_t)i*CH + t] * phi_b[i];
        qq += phi_w[(size_t)i*CH + t] * theta_b[i];
      }
      tphi[t] = tp; q[t] = qq;
      lbuf[t] = (t < CI) ? theta_b[t]*phi_b[t] : 0.f;
      __syncthreads();
      for (int s2 = 128; s2 > 0; s2 >>= 1) { if (t < s2) lbuf[t] += lbuf[t + s2]; __syncthreads(); }
      if (t == 0) tb[0] = lbuf[0];
    }
    return;
  }
  // ---- streaming role: 64c x 64n tile, no LDS, no barriers (R10-verified)
  const int b = blockIdx.z, c0 = blockIdx.y*64, n0 = blockIdx.x*64;
  const int lane8 = t & 7, rq = t >> 3;        // rq 0..31
  const float* xp = x + ((size_t)b*CH + c0)*NSP + n0 + lane8*8;
  u16* xbp = xb + ((size_t)b*CH + c0)*NSP + n0 + lane8*8;
  #pragma unroll
  for (int p = 0; p < 2; ++p) {
    const int cl = rq + p*32;
    float4 v0 = *(const float4*)(xp + (size_t)cl*NSP);
    float4 v1 = *(const float4*)(xp + (size_t)cl*NSP + 4);
    float ps = v0.x+v0.y+v0.z+v0.w + v1.x+v1.y+v1.z+v1.w;
    #pragma unroll
    for (int o = 1; o < 8; o <<= 1) ps += __shfl_xor(ps, o, 64);
    if (lane8 == 0) psum[((size_t)b*64 + blockIdx.x)*CH + c0 + cl] = ps;
    bf16x8 bv;
    bv[0]=(short)f2b(v0.x); bv[1]=(short)f2b(v0.y); bv[2]=(short)f2b(v0.z); bv[3]=(short)f2b(v0.w);
    bv[4]=(short)f2b(v1.x); bv[5]=(short)f2b(v1.y); bv[6]=(short)f2b(v1.z); bv[7]=(short)f2b(v1.w);
    *(bf16x8*)(xbp + (size_t)cl*NSP) = bv;
  }
}

// ---------------- kernel 2: Gram partials, 64x64 symmetric tiles (10 of 16), KC=4
__global__ __launch_bounds__(256) void k_gram(const u16* __restrict__ xb, float* __restrict__ Sp) {
  __shared__ u16 As[64*64];   // 8 KB
  __shared__ u16 Bs[64*64];   // 8 KB
  const int TIa[10] = {0,0,0,0,1,1,1,2,2,3};
  const int TJa[10] = {0,1,2,3,1,2,3,2,3,3};
  const int L = blockIdx.x;
  const int wk = (L & 7) * 80 + (L >> 3);   // bijective: 640 = 8*80
  const int b = wk / 40;
  const int rem = wk % 40;
  const int kc = rem / 10;
  const int tile = rem % 10;
  const int ti = TIa[tile], tj = TJa[tile];
  const int m_base = ti*64, n_base = tj*64;
  const bool diag = (ti == tj);
  const int t = threadIdx.x, wv = t >> 6, l = t & 63;
  const int wr = wv >> 1, wc = wv & 1;
  const int lr = l & 15, lkb = l >> 4;      // fragment row lane, k sub-block
  const int sr8 = l >> 3, ss = l & 7;       // staging: row-within-8, 16B slot
  const u16* xa = xb + (size_t)b*CH*NSP;
  const int kbeg = kc * (NSP/KC);
  f32x4 acc[2][2];
  #pragma unroll
  for (int i = 0; i < 2; ++i)
    #pragma unroll
    for (int j = 0; j < 2; ++j) acc[i][j] = (f32x4){0.f,0.f,0.f,0.f};

  for (int kk = 0; kk < 16; ++kk) {
    const int kpos = kbeg + kk*64;
    #pragma unroll
    for (int j = 0; j < 2; ++j) {
      const int g = wv*2 + j;               // 0..7
      const int r = g*8 + sr8;              // 0..63
      async16(&As[g*512], xa + (size_t)(m_base + r)*NSP + kpos + ((ss ^ (r & 7)) * 8));
    }
    if (!diag) {
      #pragma unroll
      for (int j = 0; j < 2; ++j) {
        const int g = wv*2 + j;
        const int r = g*8 + sr8;
        async16(&Bs[g*512], xa + (size_t)(n_base + r)*NSP + kpos + ((ss ^ (r & 7)) * 8));
      }
    }
    __syncthreads();
    const u16* bsrc = diag ? As : Bs;
    #pragma unroll
    for (int ks = 0; ks < 2; ++ks) {
      bf16x8 A[2], Bf[2];
      #pragma unroll
      for (int mt = 0; mt < 2; ++mt) {
        const int ra = wr*32 + mt*16 + lr;
        A[mt] = *(const bf16x8*)(As + ra*64 + (((ks*4 + lkb) ^ (ra & 7)) * 8));
      }
      #pragma unroll
      for (int nt = 0; nt < 2; ++nt) {
        const int rb = wc*32 + nt*16 + lr;
        Bf[nt] = *(const bf16x8*)(bsrc + rb*64 + (((ks*4 + lkb) ^ (rb & 7)) * 8));
      }
      #pragma unroll
      for (int mt = 0; mt < 2; ++mt)
        #pragma unroll
        for (int nt = 0; nt < 2; ++nt)
          acc[mt][nt] = __builtin_amdgcn_mfma_f32_16x16x32_bf16(A[mt], Bf[nt], acc[mt][nt], 0, 0, 0);
    }
    __syncthreads();
  }
  float* Sb = Sp + (size_t)((b*KC + kc)*10 + tile)*4096;
  const int r0 = (l >> 4) * 4;
  #pragma unroll
  for (int mt = 0; mt < 2; ++mt)
    #pragma unroll
    for (int nt = 0; nt < 2; ++nt)
      #pragma unroll
      for (int rr = 0; rr < 4; ++rr) {
        const int lm = wr*32 + mt*16 + r0 + rr;
        const int lc = wc*32 + nt*16 + lr;
        Sb[lm*64 + lc] = acc[mt][nt][rr];
      }
}

// ---------------- fused: reduce Sp tiles -> S (with symmetric mirror) + per-batch vectors
__global__ __launch_bounds__(256) void k_redvec(const float* __restrict__ Sp,
    const float* __restrict__ psum, const float* __restrict__ E,
    const float* __restrict__ KT, const float* __restrict__ q,
    float* __restrict__ S, float* __restrict__ KS, float* __restrict__ Es,
    float* __restrict__ qs) {
  __shared__ float tl[64*65 + 8];
  const int b = blockIdx.y, xx = blockIdx.x, t = threadIdx.x;
  if (xx < 10) {
    const int TIa[10] = {0,0,0,0,1,1,1,2,2,3};
    const int TJa[10] = {0,1,2,3,1,2,3,2,3,3};
    const int ti = TIa[xx], tj = TJa[xx];
    const int row0 = ti*64, col0 = tj*64;
    float* Sb = S + (size_t)b*CH*CH;
    float4 sum[4];
    #pragma unroll
    for (int k = 0; k < 4; ++k) {
      const int slot = t + k*256;
      const int r = slot >> 4, c4 = (slot & 15) * 4;
      float4 s = {0.f,0.f,0.f,0.f};
      #pragma unroll
      for (int kc = 0; kc < KC; ++kc) {
        const float* p = Sp + (size_t)((b*KC + kc)*10 + xx)*4096;
        float4 v = *(const float4*)(p + r*64 + c4);
        s.x += v.x; s.y += v.y; s.z += v.z; s.w += v.w;
      }
      sum[k] = s;
      *(float4*)(Sb + (size_t)(row0 + r)*CH + col0 + c4) = s;
    }
    if (ti != tj) {                            // mirror to lower triangle
      #pragma unroll
      for (int k = 0; k < 4; ++k) {
        const int slot = t + k*256;
        const int r = slot >> 4, c4 = (slot & 15) * 4;
        tl[r*65 + c4+0] = sum[k].x; tl[r*65 + c4+1] = sum[k].y;
        tl[r*65 + c4+2] = sum[k].z; tl[r*65 + c4+3] = sum[k].w;
      }
      __syncthreads();
      #pragma unroll
      for (int k = 0; k < 4; ++k) {
        const int slot = t + k*256;
        const int r = slot >> 4, c4 = (slot & 15) * 4;
        float4 v = { tl[(c4+0)*65 + r], tl[(c4+1)*65 + r],
                     tl[(c4+2)*65 + r], tl[(c4+3)*65 + r] };
        *(float4*)(Sb + (size_t)(col0 + r)*CH + row0 + c4) = v;
      }
    }
  } else {
    float s = 0.f;
    for (int nb = 0; nb < 64; ++nb) s += psum[((size_t)b*64 + nb)*CH + t];
    tl[t] = s;
    __syncthreads();
    float ks = 0.f;
    for (int a = 0; a < CH; ++a) ks += KT[(size_t)a*CH + t] * tl[a];
    KS[(size_t)b*CH + t] = ks;
    float es = 0.f;
    for (int c = 0; c < CH; ++c) es += E[(size_t)t*CH + c] * tl[c];
    Es[(size_t)b*CH + t] = es;
    float p = q[t] * tl[t];
    #pragma unroll
    for (int o = 1; o < 64; o <<= 1) p += __shfl_xor(p, o, 64);
    if ((t & 63) == 0) tl[4160 + (t >> 6)] = p;
    __syncthreads();
    if (t == 0) qs[b] = tl[4160] + tl[4161] + tl[4162] + tl[4163];
  }
}

// ---------------- k_RP: fused R = E·S (LDS-resident) then P = (inv/N)(R·KT + rank1s) + I
__global__ __launch_bounds__(256) void k_RP(const float* __restrict__ S,
    const float* __restrict__ E, const float* __restrict__ KT,
    const float* __restrict__ q, const float* __restrict__ KS,
    const float* __restrict__ Es, const float* __restrict__ qs,
    const float* __restrict__ wg, const float* __restrict__ tphi,
    const float* __restrict__ inv, const float* __restrict__ dconst,
    const float* __restrict__ tb, u16* __restrict__ Pb, float* __restrict__ dv) {
  __shared__ float lEt[2048];
  __shared__ float lRt[2048];
  __shared__ float red[32];
  const int b = blockIdx.y, o0 = blockIdx.x*8, t = threadIdx.x;
  #pragma unroll
  for (int k = 0; k < 8; ++k) { int idx = k*256 + t;
    lEt[idx] = E[(size_t)(o0 + (idx & 7))*CH + (idx >> 3)]; }
  __syncthreads();
  const float* Sb = S + (size_t)b*CH*CH;
  float acc[8] = {0.f};
  for (int c = 0; c < CH; ++c) {
    float sv = Sb[(size_t)c*CH + t];
    #pragma unroll
    for (int r = 0; r < 8; ++r) acc[r] += lEt[c*8 + r] * sv;
  }
  #pragma unroll
  for (int r = 0; r < 8; ++r) lRt[t*8 + r] = acc[r];
  const float qt = q[t];
  #pragma unroll
  for (int r = 0; r < 8; ++r) {
    float p = acc[r] * qt;
    #pragma unroll
    for (int o = 1; o < 64; o <<= 1) p += __shfl_xor(p, o, 64);
    if ((t & 63) == 0) red[r*4 + (t >> 6)] = p;
  }
  __syncthreads();
  float acc2[8] = {0.f};
  for (int a = 0; a < CH; ++a) {
    float kv = KT[(size_t)a*CH + t];
    #pragma unroll
    for (int r = 0; r < 8; ++r) acc2[r] += lRt[a*8 + r] * kv;
  }
  const float ksv = KS[(size_t)b*CH + t], tpv = tphi[t];
  u16* Pbb = Pb + (size_t)b*CH*CH;
  #pragma unroll
  for (int r = 0; r < 8; ++r) {
    int o = o0 + r;
    float val = (acc2[r] + wg[o]*ksv + (Es[(size_t)b*CH + o] + (float)NSP*wg[o])*tpv)
                * inv[o] * (1.f/(float)NSP);
    if (o == t) val += 1.f;      // fold residual: P + I
    Pbb[(size_t)o*CH + t] = f2b(val);
  }
  if (t < 8) {
    int o = o0 + t;
    float iv = inv[o], wgo = wg[o], tb0 = tb[0];
    float rq = red[t*4] + red[t*4+1] + red[t*4+2] + red[t*4+3];
    float t2 = rq + wgo*qs[b] + Es[(size_t)b*CH + o]*tb0;
    dv[(size_t)b*CH + o] = iv*(t2*(1.f/(float)NSP) + wgo*tb0) + dconst[o];
  }
}

// ---------------- apply: out = (P+I) X + d 1^T — stages Xb [c][n], transposes in
// REGISTERS (8x ushort4 loads -> 4x ds_write_b128), same LDS layout as R12:
// tl[n*256 + ((o ^ K(n))<<3)], K(n) = (n&7)^(n>>3). Write/read both at the b128
// inherent 8-lane/cluster minimum (XOR-linear lane->cluster map, derived).
// grid (NSP/64, BATCH), block 512 = 8 waves, wave tile 32 rows x 64 cols.
__global__ __launch_bounds__(512, 4) void k_apply(const u16* __restrict__ Pb,
    const u16* __restrict__ xb, const float* __restrict__ dv,
    float* __restrict__ out) {
  __shared__ union {
    u16   tl[64*256];        // 32 KB bf16 transposed tile (XOR-swizzled octets)
    float fe[8][16][68];     // 34 KB per-wave f32 epilogue buffers (stride 68)
  } sm;
  const int b = blockIdx.y, n0 = blockIdx.x*64;
  const int t = threadIdx.x, w = t >> 6, l = t & 63;
  {
    const u16* src = xb + (size_t)b*CH*NSP + n0;
    const int o = t >> 4;                      // c-octet 0..31
    const int nq = t & 15;                     // n-quad base: n = nq*4 + j
    ushort4 ld[8];
    #pragma unroll
    for (int i = 0; i < 8; ++i)
      ld[i] = *(const ushort4*)(src + (size_t)(o*8 + i)*NSP + nq*4);
    #pragma unroll
    for (int j = 0; j < 4; ++j) {
      const int n = nq*4 + j;
      const int K = (n & 7) ^ (n >> 3);
      bf16x8 wv;
      #pragma unroll
      for (int i = 0; i < 8; ++i) {
        ushort4 v = ld[i];
        wv[i] = (short)((j == 0) ? v.x : (j == 1) ? v.y : (j == 2) ? v.z : v.w);
      }
      *(bf16x8*)(sm.tl + n*256 + ((o ^ K) << 3)) = wv;
    }
  }
  __syncthreads();
  const int m0 = w*32;
  const int lr = l & 15, lkb = l >> 4;   // k sub-block 0..3 (8 elems each)
  const u16* Pp = Pb + (size_t)b*CH*CH;
  f32x4 acc[2][4];
  #pragma unroll
  for (int i = 0; i < 2; ++i)
    #pragma unroll
    for (int j = 0; j < 4; ++j) acc[i][j] = (f32x4){0.f,0.f,0.f,0.f};
  #pragma unroll
  for (int kk = 0; kk < 8; ++kk) {
    bf16x8 A[2], Bf[4];
    #pragma unroll
    for (int mt = 0; mt < 2; ++mt)
      A[mt] = *(const bf16x8*)(Pp + (size_t)(m0 + mt*16 + lr)*CH + kk*32 + lkb*8);
    #pragma unroll
    for (int nt = 0; nt < 4; ++nt) {
      const int row = nt*16 + lr;
      const int K = (row & 7) ^ (row >> 3);
      const int slot = kk*4 + lkb;
      Bf[nt] = *(const bf16x8*)(sm.tl + row*256 + ((slot ^ K) * 8));
    }
    #pragma unroll
    for (int mt = 0; mt < 2; ++mt)
      #pragma unroll
      for (int nt = 0; nt < 4; ++nt)
        acc[mt][nt] = __builtin_amdgcn_mfma_f32_16x16x32_bf16(A[mt], Bf[nt], acc[mt][nt], 0, 0, 0);
  }
  __syncthreads();                     // tile dead; reuse LDS for epilogue
  float* ob = out + (size_t)b*CH*NSP;
  const int r0 = (l >> 4) * 4;
  #pragma unroll
  for (int mt = 0; mt < 2; ++mt) {
    #pragma unroll
    for (int rr = 0; rr < 4; ++rr) {
      float dval = dv[(size_t)b*CH + m0 + mt*16 + r0 + rr];
      #pragma unroll
      for (int nt = 0; nt < 4; ++nt)
        sm.fe[w][r0 + rr][nt*16 + lr] = acc[mt][nt][rr] + dval;
    }
    #pragma unroll
    for (int i = 0; i < 4; ++i) {
      int s = l + 64*i;
      int rrow = s >> 4, c4 = (s & 15) * 4;
      float4 v = *(const float4*)&sm.fe[w][rrow][c4];
      *(float4*)&ob[(size_t)(m0 + mt*16 + rrow)*NSP + n0 + c4] = v;
    }
  }
}

// ---------------- workspace layout (bytes) — Xb lives in ws
static constexpr size_t XB_OFF = 0;              // bf16 [16][256][4096]  33,554,432
static constexpr size_t S_OFF  = 33554432;       // f32  [16][256][256]    4,194,304
static constexpr size_t PB_OFF = 37748736;       // bf16 [16][256][256]    2,097,152
static constexpr size_t PS_OFF = 39845888;       // f32  [16][64][256]     1,048,576
static constexpr size_t E_OFF  = 40894464;       // f32  [256][256]          262,144
static constexpr size_t KT_OFF = 41156608;       // f32  [256][256]          262,144
static constexpr size_t WG_OFF = 41418752;       // f32 [256] (1K pad each follows)
static constexpr size_t TP_OFF = 41419776;
static constexpr size_t QV_OFF = 41420800;
static constexpr size_t IV_OFF = 41421824;
static constexpr size_t DC_OFF = 41422848;
static constexpr size_t TB_OFF = 41423872;
static constexpr size_t KS_OFF = 41424896;       // f32 [16][256] 16,384
static constexpr size_t ES_OFF = 41441280;       // f32 [16][256] 16,384
static constexpr size_t QS_OFF = 41457664;       // f32 [16] (1K pad)
static constexpr size_t DV_OFF = 41458688;       // f32 [16][256] 16,384

extern "C" void kernel_launch(void* const* d_in, const int* in_sizes, int n_in,
                              void* d_out, int out_size, void* d_ws, size_t ws_size,
                              hipStream_t stream) {
  const float* x       = (const float*)d_in[0];
  const float* g_w     = (const float*)d_in[1];
  const float* g_b     = (const float*)d_in[2];
  const float* theta_w = (const float*)d_in[3];
  const float* theta_b = (const float*)d_in[4];
  const float* phi_w   = (const float*)d_in[5];
  const float* phi_b   = (const float*)d_in[6];
  const float* w_w     = (const float*)d_in[7];
  const float* w_b     = (const float*)d_in[8];
  const float* bn_g    = (const float*)d_in[9];
  const float* bn_b    = (const float*)d_in[10];
  const float* bn_m    = (const float*)d_in[11];
  const float* bn_v    = (const float*)d_in[12];
  float* out = (float*)d_out;
  char* ws = (char*)d_ws;
  u16*   Xb = (u16*)(ws + XB_OFF);
  float* S  = (float*)(ws + S_OFF);
  u16*   Pb = (u16*)(ws + PB_OFF);
  float* PS = (float*)(ws + PS_OFF);
  float* E  = (float*)(ws + E_OFF);
  float* KT = (float*)(ws + KT_OFF);
  float* WG = (float*)(ws + WG_OFF);
  float* TP = (float*)(ws + TP_OFF);
  float* QV = (float*)(ws + QV_OFF);
  float* IV = (float*)(ws + IV_OFF);
  float* DC = (float*)(ws + DC_OFF);
  float* TB = (float*)(ws + TB_OFF);
  float* KS = (float*)(ws + KS_OFF);
  float* ES = (float*)(ws + ES_OFF);
  float* QS = (float*)(ws + QS_OFF);
  float* DV = (float*)(ws + DV_OFF);
  // d_out scratch: compact Sp [33.5MB, +10.5MB). Dead before k_apply rewrites d_out.
  float* Sp = (float*)((char*)d_out + 33554432);

  k_prep  <<<dim3(64, 4, BATCH+1),        256, 0, stream>>>(x, Xb, PS,
            w_w, g_w, g_b, theta_w, theta_b, phi_w, phi_b, w_b, bn_g, bn_b, bn_m, bn_v,
            E, KT, WG, TP, QV, IV, DC, TB);
  k_gram  <<<dim3(640),                   256, 0, stream>>>(Xb, Sp);
  k_redvec<<<dim3(11, BATCH),             256, 0, stream>>>(Sp, PS, E, KT, QV, S, KS, ES, QS);
  k_RP    <<<dim3(32, BATCH),             256, 0, stream>>>(S, E, KT, QV, KS, ES, QS, WG, TP, IV, DC, TB, Pb, DV);
  k_apply <<<dim3(NSP/64, BATCH),         512, 0, stream>>>(Pb, Xb, DV, out);
}